// Round 4
// baseline (158.786 us; speedup 1.0000x reference)
//
#include <hip/hip_runtime.h>
#include <math.h>

#define EMBED_DIM 64
#define NUM_EXPERTS 4

// One THREAD per token. Logits computed as a strictly SEQUENTIAL f32 chain
// over d=0..63 with SEPARATE multiply and add roundings (NO FMA). This
// reproduces numpy's einsum('nd,ed->ne') C sum-of-products loop (einsum with
// optimize=False never calls BLAS; its inner loop is `sum += a[d]*b[d]` with
// two roundings per step). hipcc defaults to -ffp-contract=fast, which would
// silently fuse mul+add back into FMA — the pragma below disables that.
__global__ __launch_bounds__(256) void gate_kernel(
    const float* __restrict__ x,
    const float* __restrict__ W,
    float* __restrict__ wout,     // [n,4] dense routing weights
    float* __restrict__ iout,     // [n,2] top-k indices, stored as float
    int n)
{
#pragma clang fp contract(off)
    const int tok = blockIdx.x * blockDim.x + threadIdx.x;
    if (tok >= n) return;

    const float4* xr = reinterpret_cast<const float4*>(x) + (size_t)tok * 16;
    const float4* W4 = reinterpret_cast<const float4*>(W);  // wave-uniform -> scalar loads

    float s0 = 0.0f, s1 = 0.0f, s2 = 0.0f, s3 = 0.0f;

    #pragma unroll
    for (int j = 0; j < 16; ++j) {
        const float4 xv = xr[j];
        const float4 a = W4[0 * 16 + j];
        const float4 b = W4[1 * 16 + j];
        const float4 c = W4[2 * 16 + j];
        const float4 d = W4[3 * 16 + j];
        // strict d-order, mul rounded then add rounded (no contraction):
        s0 = s0 + xv.x * a.x; s0 = s0 + xv.y * a.y;
        s0 = s0 + xv.z * a.z; s0 = s0 + xv.w * a.w;
        s1 = s1 + xv.x * b.x; s1 = s1 + xv.y * b.y;
        s1 = s1 + xv.z * b.z; s1 = s1 + xv.w * b.w;
        s2 = s2 + xv.x * c.x; s2 = s2 + xv.y * c.y;
        s2 = s2 + xv.z * c.z; s2 = s2 + xv.w * c.w;
        s3 = s3 + xv.x * d.x; s3 = s3 + xv.y * d.y;
        s3 = s3 + xv.z * d.z; s3 = s3 + xv.w * d.w;
    }

    // top-1: strict > so ties break to the LOWER index (lax.top_k semantics).
    int   i1 = 0;  float v1 = s0;
    if (s1 > v1) { v1 = s1; i1 = 1; }
    if (s2 > v1) { v1 = s2; i1 = 2; }
    if (s3 > v1) { v1 = s3; i1 = 3; }
    // top-2 among the rest, same tie rule.
    int   i2 = -1; float v2 = -INFINITY;
    if (i1 != 0 && s0 > v2) { v2 = s0; i2 = 0; }
    if (i1 != 1 && s1 > v2) { v2 = s1; i2 = 1; }
    if (i1 != 2 && s2 > v2) { v2 = s2; i2 = 2; }
    if (i1 != 3 && s3 > v2) { v2 = s3; i2 = 3; }

    // 2-way softmax on f32 topk logits (v1 >= v2 so exp arg <= 0).
    const float e2  = expf(v2 - v1);
    const float den = 1.0f + e2;
    const float p1  = 1.0f / den;
    const float p2  = e2 / den;

    float4 wv;
    wv.x = (i1 == 0) ? p1 : ((i2 == 0) ? p2 : 0.0f);
    wv.y = (i1 == 1) ? p1 : ((i2 == 1) ? p2 : 0.0f);
    wv.z = (i1 == 2) ? p1 : ((i2 == 2) ? p2 : 0.0f);
    wv.w = (i1 == 3) ? p1 : ((i2 == 3) ? p2 : 0.0f);
    reinterpret_cast<float4*>(wout)[tok] = wv;

    float2 iv;
    iv.x = (float)i1;
    iv.y = (float)i2;
    reinterpret_cast<float2*>(iout)[tok] = iv;
}

extern "C" void kernel_launch(void* const* d_in, const int* in_sizes, int n_in,
                              void* d_out, int out_size, void* d_ws, size_t ws_size,
                              hipStream_t stream) {
    const float* x = (const float*)d_in[0];
    const float* W = (const float*)d_in[1];
    const int n = in_sizes[0] / EMBED_DIM;   // 2097152

    float* wout = (float*)d_out;                    // n*4 floats
    float* iout = wout + (size_t)n * NUM_EXPERTS;   // n*2 indices stored as float

    const int block = 256;
    const int grid  = (n + block - 1) / block;      // 8192
    hipLaunchKernelGGL(gate_kernel, dim3(grid), dim3(block), 0, stream,
                       x, W, wout, iout, n);
}

// Round 5
// 116.464 us; speedup vs baseline: 1.3634x; 1.3634x over previous
//
#include <hip/hip_runtime.h>
#include <math.h>

#define EMBED_DIM 64
#define NUM_EXPERTS 4
#define THREADS 128
#define TOK_PER_BLOCK 128
#define CHUNKS (TOK_PER_BLOCK * 16)   // 2048 float4 chunks = 32 KB LDS

// One thread per token, but token rows are staged through LDS so global
// reads are perfectly coalesced (each global_load_lds covers a contiguous
// 1KB span). LDS dest is linear (global_load_lds requirement); the per-lane
// GLOBAL source is inverse-XOR-swizzled, and the compute-side ds_read uses
// the same XOR -> bank-conflict-free (8 lanes per 16B bank-group = minimum).
// Arithmetic is bit-identical to the passing round-3 kernel: strictly
// sequential f32 mul-then-add chain (no FMA contraction) per logit,
// matching numpy einsum's sum-of-products order.
__global__ __launch_bounds__(THREADS) void gate_kernel(
    const float* __restrict__ x,
    const float* __restrict__ W,
    float* __restrict__ wout,     // [n,4] dense routing weights
    float* __restrict__ iout,     // [n,2] top-k indices, stored as float
    int n)
{
#pragma clang fp contract(off)
    __shared__ float4 lds[CHUNKS];

    const int t    = threadIdx.x;        // 0..127, also in-block token id
    const int wave = t >> 6;
    const int lane = t & 63;
    const size_t blockChunk = (size_t)blockIdx.x * CHUNKS;  // global float4 idx

    const float4* x4 = reinterpret_cast<const float4*>(x);

    // Stage 128 rows (32 KB). Wave w, iter i covers linear LDS chunks
    // [(w*16+i)*64, +64); lane l's 16B lands at base + l*16 (HW rule).
    // Source chunk for linear chunk L: tk=L>>4, c=L&15 -> tk*16 + (c ^ (tk&7)).
    #pragma unroll
    for (int i = 0; i < 16; ++i) {
        const int base = (wave * 16 + i) * 64;
        const int L  = base + lane;
        const int tk = L >> 4;
        const int c  = L & 15;
        const int gc = (tk << 4) | (c ^ (tk & 7));
        __builtin_amdgcn_global_load_lds(
            (const __attribute__((address_space(1))) void*)(x4 + blockChunk + gc),
            (__attribute__((address_space(3))) void*)&lds[base],
            16, 0, 0);
    }
    __syncthreads();   // compiler drains vmcnt before s_barrier

    const float4* W4 = reinterpret_cast<const float4*>(W);  // uniform -> s_load

    float s0 = 0.0f, s1 = 0.0f, s2 = 0.0f, s3 = 0.0f;

    #pragma unroll
    for (int j = 0; j < 16; ++j) {
        const float4 xv = lds[(t << 4) | (j ^ (t & 7))];
        const float4 a = W4[0 * 16 + j];
        const float4 b = W4[1 * 16 + j];
        const float4 c = W4[2 * 16 + j];
        const float4 d = W4[3 * 16 + j];
        // strict d-order, mul rounded then add rounded (no contraction):
        s0 = s0 + xv.x * a.x; s0 = s0 + xv.y * a.y;
        s0 = s0 + xv.z * a.z; s0 = s0 + xv.w * a.w;
        s1 = s1 + xv.x * b.x; s1 = s1 + xv.y * b.y;
        s1 = s1 + xv.z * b.z; s1 = s1 + xv.w * b.w;
        s2 = s2 + xv.x * c.x; s2 = s2 + xv.y * c.y;
        s2 = s2 + xv.z * c.z; s2 = s2 + xv.w * c.w;
        s3 = s3 + xv.x * d.x; s3 = s3 + xv.y * d.y;
        s3 = s3 + xv.z * d.z; s3 = s3 + xv.w * d.w;
    }

    // top-1: strict > so ties break to the LOWER index (lax.top_k semantics).
    int   i1 = 0;  float v1 = s0;
    if (s1 > v1) { v1 = s1; i1 = 1; }
    if (s2 > v1) { v1 = s2; i1 = 2; }
    if (s3 > v1) { v1 = s3; i1 = 3; }
    // top-2 among the rest, same tie rule.
    int   i2 = -1; float v2 = -INFINITY;
    if (i1 != 0 && s0 > v2) { v2 = s0; i2 = 0; }
    if (i1 != 1 && s1 > v2) { v2 = s1; i2 = 1; }
    if (i1 != 2 && s2 > v2) { v2 = s2; i2 = 2; }
    if (i1 != 3 && s3 > v2) { v2 = s3; i2 = 3; }

    // 2-way softmax on f32 topk logits (v1 >= v2 so exp arg <= 0).
    const float e2  = expf(v2 - v1);
    const float den = 1.0f + e2;
    const float p1  = 1.0f / den;
    const float p2  = e2 / den;

    const int tok = blockIdx.x * TOK_PER_BLOCK + t;

    float4 wv;
    wv.x = (i1 == 0) ? p1 : ((i2 == 0) ? p2 : 0.0f);
    wv.y = (i1 == 1) ? p1 : ((i2 == 1) ? p2 : 0.0f);
    wv.z = (i1 == 2) ? p1 : ((i2 == 2) ? p2 : 0.0f);
    wv.w = (i1 == 3) ? p1 : ((i2 == 3) ? p2 : 0.0f);
    reinterpret_cast<float4*>(wout)[tok] = wv;

    float2 iv;
    iv.x = (float)i1;
    iv.y = (float)i2;
    reinterpret_cast<float2*>(iout)[tok] = iv;
}

extern "C" void kernel_launch(void* const* d_in, const int* in_sizes, int n_in,
                              void* d_out, int out_size, void* d_ws, size_t ws_size,
                              hipStream_t stream) {
    const float* x = (const float*)d_in[0];
    const float* W = (const float*)d_in[1];
    const int n = in_sizes[0] / EMBED_DIM;   // 2097152

    float* wout = (float*)d_out;                    // n*4 floats
    float* iout = wout + (size_t)n * NUM_EXPERTS;   // n*2 indices stored as float

    const int grid = n / TOK_PER_BLOCK;             // 16384, exact
    hipLaunchKernelGGL(gate_kernel, dim3(grid), dim3(THREADS), 0, stream,
                       x, W, wout, iout, n);
}